// Round 9
// baseline (237.148 us; speedup 1.0000x reference)
//
#include <hip/hip_runtime.h>
#include <hip/hip_fp16.h>
#include <cstdio>
#include <cstdint>

#define HH 512
#define WW 512
#define CC 32
#define BB 2
#define NN 120000
#define HWPIX (HH*WW)
#define NPTS (BB*NN)          // 240000 == total ranks (every point has a unique pixel)
#define NPIX (BB*HWPIX)       // 524288
#define NBLK (NPIX/256)       // 2048 pixel windows

__device__ __forceinline__ void h8_to_f8(float4 raw, float* o) {
    const __half2* h = (const __half2*)&raw;
    #pragma unroll
    for (int i = 0; i < 4; ++i) {
        float2 f = __half22float2(h[i]);
        o[2 * i] = f.x; o[2 * i + 1] = f.y;
    }
}

// ---------------- prep: compose weights + vecs + zero cnt (one kernel) ----------------
// M layout (floats): [0:1024) MqT, [1024:2048) MkT, [2048:3072) MvT, [3072:4096) owT
// V layout (floats): [0:32) bq'=W1@bq+in_b[:32], [32:64) bk'=W2@bk, [64:96) bv'=W3@bv,
// [96:128) PWy, [128:160) PWx, [160:192) pb3=W3@pos_b
__global__ __launch_bounds__(256) void prep(const float* __restrict__ wq, const float* __restrict__ wk,
                          const float* __restrict__ wv, const float* __restrict__ in_w,
                          const float* __restrict__ out_w,
                          const float* __restrict__ bq, const float* __restrict__ bk,
                          const float* __restrict__ bv, const float* __restrict__ in_b,
                          const float* __restrict__ pos_w, const float* __restrict__ pos_b,
                          float* __restrict__ M, float* __restrict__ V, int* __restrict__ cnt) {
    int blk = blockIdx.x;
    if (blk < 16) {
        int tid = blk * 256 + threadIdx.x;   // 0..4095
        int which = tid >> 10;
        int e = tid & 1023;
        int cp = e & 31;
        int j  = e >> 5;
        if (which < 3) {
            const float* w = (which == 0) ? wq : ((which == 1) ? wk : wv);
            const float* Wrow = in_w + (which * 32 + cp) * 32;
            float acc = 0.f;
            #pragma unroll
            for (int t = 0; t < 32; ++t) acc += Wrow[t] * w[t * 32 + j];
            M[which * 1024 + j * 32 + cp] = acc;
        } else {
            M[3 * 1024 + j * 32 + cp] = out_w[cp * 32 + j];
        }
    } else if (blk == 16) {
        int tid = threadIdx.x;
        if (tid < 32) {
            float a = 0.f, b = 0.f, c = 0.f;
            #pragma unroll
            for (int t = 0; t < 32; ++t) {
                a += in_w[tid * 32 + t] * bq[t];
                b += in_w[(32 + tid) * 32 + t] * bk[t];
                c += in_w[(64 + tid) * 32 + t] * bv[t];
            }
            V[tid]      = a + in_b[tid];
            V[32 + tid] = b;
            V[64 + tid] = c;
        } else if (tid < 128) {
            int grp = (tid - 32) >> 5;   // 0=PWy 1=PWx 2=pb3
            int cp  = tid & 31;
            float acc = 0.f;
            #pragma unroll
            for (int t = 0; t < 32; ++t) {
                float src = (grp == 0) ? pos_w[t * 2 + 0] : ((grp == 1) ? pos_w[t * 2 + 1] : pos_b[t]);
                acc += in_w[(64 + cp) * 32 + t] * src;
            }
            V[96 + grp * 32 + cp] = acc;
        }
    } else {
        for (int i = threadIdx.x; i < 2048; i += 256) cnt[i] = 0;
    }
}

// ---------------- coord -> grid, fused per-256-pixel-window count ----------------
__global__ void build_grid(const int* __restrict__ coors, int* __restrict__ grid,
                           int* __restrict__ cnt) {
    int P = blockIdx.x * blockDim.x + threadIdx.x;
    if (P >= NPTS) return;
    int b = P / NN;
    int n = P - b * NN;
    int y = coors[P * 2 + 0];
    int x = coors[P * 2 + 1];
    int pix = b * HWPIX + y * WW + x;
    grid[pix] = n;
    atomicAdd(&cnt[pix >> 8], 1);
}

// ---------------- exclusive scan of 2048 counts (single block) ----------------
__global__ __launch_bounds__(256) void scan2048(const int* __restrict__ cnt, int* __restrict__ off) {
    __shared__ int ps[256];
    int tid = threadIdx.x;
    int v[8], loc[8];
    int t = 0;
    #pragma unroll
    for (int k = 0; k < 8; ++k) { v[k] = cnt[tid * 8 + k]; loc[k] = t; t += v[k]; }
    ps[tid] = t;
    __syncthreads();
    for (int d = 1; d < 256; d <<= 1) {
        int val = ps[tid];
        int add = (tid >= d) ? ps[tid - d] : 0;
        __syncthreads();
        ps[tid] = val + add;
        __syncthreads();
    }
    int excl = (tid > 0) ? ps[tid - 1] : 0;
    #pragma unroll
    for (int k = 0; k < 8; ++k) off[tid * 8 + k] = excl + loc[k];
}

// ---------------- assign ranks: grid[pix]=rank, rmap[point]=rank ----------------
__global__ __launch_bounds__(256) void assign_ranks(const int* __restrict__ off,
                                                    int* __restrict__ grid,
                                                    int* __restrict__ rmap) {
    __shared__ int woff[4];
    int tid = threadIdx.x;
    int pix = blockIdx.x * 256 + tid;
    int n = grid[pix];
    bool occ = n >= 0;
    unsigned long long mask = __ballot(occ);
    int lane = tid & 63, wvi = tid >> 6;
    if (lane == 0) woff[wvi] = __popcll(mask);
    __syncthreads();
    int pre = 0;
    for (int w = 0; w < wvi; ++w) pre += woff[w];
    if (occ) {
        int r = off[blockIdx.x] + pre + __popcll(mask & ((1ull << lane) - 1ull));
        grid[pix] = r;
        rmap[(pix >> 18) * NN + n] = r;
    }
}

// ---------------- stage1: point-parallel LN + fused q/k/v linears ----------------
// Coalesced feats reads (point order); scattered full-line writes to rank slots.
// qh[rank] = 32 half q (64 B); kvh[rank] = 32 half k | 32 half v (128 B).
__global__ __launch_bounds__(128) void stage1(const float* __restrict__ feats,
                                              const float* __restrict__ ln_w,
                                              const float* __restrict__ ln_b,
                                              const float* __restrict__ M,
                                              const float* __restrict__ V,
                                              const int* __restrict__ rmap,
                                              __half* __restrict__ qh,
                                              __half* __restrict__ kvh) {
    int gp = blockIdx.x * 128 + threadIdx.x;   // grid = 1875 blocks exactly covers NPTS
    int r = rmap[gp];

    const float* fr = feats + ((size_t)gp << 5);
    float x[32];
    #pragma unroll
    for (int k = 0; k < 8; ++k) ((float4*)x)[k] = ((const float4*)fr)[k];

    float s1 = 0.f, s2 = 0.f;
    #pragma unroll
    for (int j = 0; j < 32; ++j) { s1 += x[j]; s2 += x[j] * x[j]; }
    float mu   = s1 * (1.f / 32.f);
    float var  = s2 * (1.f / 32.f) - mu * mu;
    float rstd = rsqrtf(var + 1e-5f);
    #pragma unroll
    for (int j = 0; j < 32; ++j) x[j] = (x[j] - mu) * rstd * ln_w[j] + ln_b[j];

    float acc[32];
    __half2 hbuf[16];

    // q' = x @ Mq + bq'  -> fp16
    #pragma unroll
    for (int c = 0; c < 32; ++c) acc[c] = V[c];
    #pragma unroll
    for (int j = 0; j < 32; ++j) {
        float xv = x[j];
        #pragma unroll
        for (int c = 0; c < 32; ++c) acc[c] += xv * M[j * 32 + c];
    }
    #pragma unroll
    for (int c = 0; c < 16; ++c) hbuf[c] = __floats2half2_rn(acc[2 * c], acc[2 * c + 1]);
    {
        float4* qd = (float4*)(qh + ((size_t)r << 5));
        #pragma unroll
        for (int k = 0; k < 4; ++k) qd[k] = ((float4*)hbuf)[k];
    }

    __half2 kvbuf[32];   // 128 B: k halves [0:16), v halves [16:32)

    // k' = x @ Mk + bk'  -> fp16
    #pragma unroll
    for (int c = 0; c < 32; ++c) acc[c] = V[32 + c];
    #pragma unroll
    for (int j = 0; j < 32; ++j) {
        float xv = x[j];
        #pragma unroll
        for (int c = 0; c < 32; ++c) acc[c] += xv * M[1024 + j * 32 + c];
    }
    #pragma unroll
    for (int c = 0; c < 16; ++c) kvbuf[c] = __floats2half2_rn(acc[2 * c], acc[2 * c + 1]);

    // v' = x @ Mv + bv'  -> fp16
    #pragma unroll
    for (int c = 0; c < 32; ++c) acc[c] = V[64 + c];
    #pragma unroll
    for (int j = 0; j < 32; ++j) {
        float xv = x[j];
        #pragma unroll
        for (int c = 0; c < 32; ++c) acc[c] += xv * M[2048 + j * 32 + c];
    }
    #pragma unroll
    for (int c = 0; c < 16; ++c) kvbuf[16 + c] = __floats2half2_rn(acc[2 * c], acc[2 * c + 1]);

    float4* kd = (float4*)(kvh + ((size_t)r << 6));
    #pragma unroll
    for (int k = 0; k < 8; ++k) kd[k] = ((float4*)kvbuf)[k];
}

// ---------------- stage23: fused attention + out-proj + canvas write ----------------
// Block = one 256-pixel window (ranks are pixel-ordered => window ranks are consecutive).
// Phase A: one lane per point (both heads in-lane), o -> fp16 LDS.
// Phase B: all 256 threads write the canvas (covers empty pixels with zeros).
__global__ __launch_bounds__(256) void stage23(const int* __restrict__ grid,
                                               const __half* __restrict__ qh,
                                               const __half* __restrict__ kvh,
                                               const float* __restrict__ M,
                                               const float* __restrict__ V,
                                               const float* __restrict__ in_b,
                                               const float* __restrict__ out_b,
                                               float* __restrict__ out) {
    __shared__ __half2 lso[256 * 17];   // 17 half2 (68 B) stride per point
    __shared__ int lsr[256], lsp[256];
    __shared__ int woff[4];

    int w = (blockIdx.x & 7) * 256 + (blockIdx.x >> 3);   // XCD-swizzled window index
    int tid = threadIdx.x;
    int pix = w * 256 + tid;

    int rk = grid[pix];
    bool occ = rk >= 0;
    unsigned long long mask = __ballot(occ);
    int lane = tid & 63, wvi = tid >> 6;
    if (lane == 0) woff[wvi] = __popcll(mask);
    __syncthreads();
    int pre = 0;
    for (int ww = 0; ww < wvi; ++ww) pre += woff[ww];
    int cnt = woff[0] + woff[1] + woff[2] + woff[3];
    int slot = -1;
    if (occ) {
        slot = pre + __popcll(mask & ((1ull << lane) - 1ull));
        lsr[slot] = rk;
        lsp[slot] = tid;
    }
    __syncthreads();

    const int DYC[9] = {0,-1,1,0,-1,1,0,-1,1};
    const int DXC[9] = {0,0,0,1,1,1,-1,-1,-1};

    // ---- phase A: attention, one thread per point ----
    if (tid < cnt) {
        int i = tid;
        int r = lsr[i];
        int pixl = w * 256 + lsp[i];
        int b = pixl >> 18;
        int p = pixl & (HWPIX - 1);
        int y = p >> 9, x = p & 511;

        float qf[32];
        {
            const float4* q4 = (const float4*)(qh + ((size_t)r << 5));
            float4 r0 = q4[0], r1 = q4[1], r2 = q4[2], r3 = q4[3];
            h8_to_f8(r0, qf); h8_to_f8(r1, qf + 8); h8_to_f8(r2, qf + 16); h8_to_f8(r3, qf + 24);
        }

        int nr[9];
        #pragma unroll
        for (int s = 0; s < 9; ++s) {
            int sy = y + DYC[s], sx = x + DXC[s];
            nr[s] = (sy >= 0 && sy < HH && sx >= 0 && sx < WW) ? grid[(b << 18) + (sy << 9) + sx] : -1;
        }

        float eb0 = 0.f, eb1 = 0.f;
        #pragma unroll
        for (int c = 0; c < 16; ++c) {
            eb0 += qf[c]      * in_b[32 + c];
            eb1 += qf[16 + c] * in_b[48 + c];
        }

        float lg0[9], lg1[9];
        #pragma unroll
        for (int s = 0; s < 9; ++s) {
            float d0 = eb0, d1 = eb1;
            if (nr[s] >= 0) {
                const float4* kp = (const float4*)(kvh + ((size_t)nr[s] << 6));
                float kf[32];
                h8_to_f8(kp[0], kf);      h8_to_f8(kp[1], kf + 8);
                h8_to_f8(kp[2], kf + 16); h8_to_f8(kp[3], kf + 24);
                #pragma unroll
                for (int c = 0; c < 16; ++c) {
                    d0 += qf[c]      * kf[c];
                    d1 += qf[16 + c] * kf[16 + c];
                }
            }
            lg0[s] = d0 * 0.25f;   // 1/sqrt(HD=16)
            lg1[s] = d1 * 0.25f;
        }
        float m0 = lg0[0], m1 = lg1[0];
        #pragma unroll
        for (int s = 1; s < 9; ++s) { m0 = fmaxf(m0, lg0[s]); m1 = fmaxf(m1, lg1[s]); }
        float l0 = 0.f, l1 = 0.f;
        #pragma unroll
        for (int s = 0; s < 9; ++s) {
            lg0[s] = __expf(lg0[s] - m0); l0 += lg0[s];
            lg1[s] = __expf(lg1[s] - m1); l1 += lg1[s];
        }

        float o[32];
        #pragma unroll
        for (int c = 0; c < 32; ++c) o[c] = 0.f;
        float wdy0 = 0.f, wdx0 = 0.f, woc0 = 0.f;
        float wdy1 = 0.f, wdx1 = 0.f, woc1 = 0.f;
        #pragma unroll
        for (int s = 0; s < 9; ++s) {
            if (nr[s] >= 0) {
                float w0 = lg0[s], w1 = lg1[s];
                const float4* vp = (const float4*)(kvh + ((size_t)nr[s] << 6)) + 4;
                float vf[32];
                h8_to_f8(vp[0], vf);      h8_to_f8(vp[1], vf + 8);
                h8_to_f8(vp[2], vf + 16); h8_to_f8(vp[3], vf + 24);
                #pragma unroll
                for (int c = 0; c < 16; ++c) {
                    o[c]      += w0 * vf[c];
                    o[16 + c] += w1 * vf[16 + c];
                }
                wdy0 += w0 * (float)DYC[s]; wdx0 += w0 * (float)DXC[s]; woc0 += w0;
                wdy1 += w1 * (float)DYC[s]; wdx1 += w1 * (float)DXC[s]; woc1 += w1;
            }
        }
        float rl0 = 1.f / l0, rl1 = 1.f / l1;
        #pragma unroll
        for (int c = 0; c < 16; ++c) {
            o[c]      = (o[c]      + wdy0 * V[96 + c]      + wdx0 * V[128 + c]      + woc0 * V[160 + c])      * rl0 + in_b[64 + c];
            o[16 + c] = (o[16 + c] + wdy1 * V[96 + 16 + c] + wdx1 * V[128 + 16 + c] + woc1 * V[160 + 16 + c]) * rl1 + in_b[80 + c];
        }

        // out projection: all 32 channels, wave-uniform (scalarized) weights
        float acc[32];
        #pragma unroll
        for (int c = 0; c < 32; ++c) acc[c] = out_b[c];
        #pragma unroll
        for (int j = 0; j < 32; ++j) {
            float vj = o[j];
            #pragma unroll
            for (int c = 0; c < 32; ++c) acc[c] += vj * M[3072 + j * 32 + c];
        }

        // pack fp16 into LDS row (stride 17 half2)
        __half2* lrow = lso + i * 17;
        #pragma unroll
        for (int c = 0; c < 16; ++c) lrow[c] = __floats2half2_rn(acc[2 * c], acc[2 * c + 1]);
    }
    __syncthreads();

    // ---- phase B: canvas write (all 256 threads; 256 B contiguous per wave-instr) ----
    int b = pix >> 18;
    int p = pix & (HWPIX - 1);
    float* outb = out + (size_t)b * CC * HWPIX + p;
    if (occ) {
        const __half2* lrow = lso + slot * 17;
        #pragma unroll
        for (int c2 = 0; c2 < 16; ++c2) {
            float2 f = __half22float2(lrow[c2]);
            outb[(2 * c2) * HWPIX]     = f.x;
            outb[(2 * c2 + 1) * HWPIX] = f.y;
        }
    } else {
        #pragma unroll
        for (int cc = 0; cc < 32; ++cc) outb[cc * HWPIX] = 0.f;
    }
}

extern "C" void kernel_launch(void* const* d_in, const int* in_sizes, int n_in,
                              void* d_out, int out_size, void* d_ws, size_t ws_size,
                              hipStream_t stream) {
    const float* feats = (const float*)d_in[0];
    const int*   coors = (const int*)d_in[1];
    const float* ln_w  = (const float*)d_in[2];
    const float* ln_b  = (const float*)d_in[3];
    const float* wq    = (const float*)d_in[4];
    const float* bq    = (const float*)d_in[5];
    const float* wk    = (const float*)d_in[6];
    const float* bk    = (const float*)d_in[7];
    const float* wv    = (const float*)d_in[8];
    const float* bv    = (const float*)d_in[9];
    const float* pos_w = (const float*)d_in[10];
    const float* pos_b = (const float*)d_in[11];
    const float* in_w  = (const float*)d_in[12];
    const float* in_b  = (const float*)d_in[13];
    const float* out_w = (const float*)d_in[14];
    const float* out_b = (const float*)d_in[15];

    // workspace layout
    int*    grid = (int*)d_ws;                                          // NPIX ints
    __half* qh   = (__half*)((int*)d_ws + NPIX);                        // NPTS*32 halves (q)
    __half* kvh  = qh + (size_t)NPTS * 32;                              // NPTS*64 halves (k|v)
    float*  M    = (float*)(kvh + (size_t)NPTS * 64);                   // 4096
    float*  V    = M + 4096;                                            // 192
    size_t need = (size_t)NPIX * 4 + (size_t)NPTS * 96 * 2 + (4096 + 192) * 4;
    if (ws_size < need) {
        fprintf(stderr, "kernel_launch: ws too small: %zu < %zu\n", ws_size, need);
        return;
    }
    // scratch in the tail of d_out (stage23 rewrites all of d_out at the end):
    int* cnt  = (int*)d_out + (out_size - 4096);
    int* off  = cnt + 2048;
    int* rmap = (int*)d_out + (out_size - 4096 - NPTS);

    hipMemsetAsync(grid, 0xFF, (size_t)NPIX * sizeof(int), stream);   // grid = -1
    prep<<<18, 256, 0, stream>>>(wq, wk, wv, in_w, out_w, bq, bk, bv, in_b, pos_w, pos_b, M, V, cnt);
    build_grid<<<(NPTS + 255) / 256, 256, 0, stream>>>(coors, grid, cnt);
    scan2048<<<1, 256, 0, stream>>>(cnt, off);
    assign_ranks<<<NBLK, 256, 0, stream>>>(off, grid, rmap);
    stage1<<<NPTS / 128, 128, 0, stream>>>(feats, ln_w, ln_b, M, V, rmap, qh, kvh);
    stage23<<<NBLK, 256, 0, stream>>>(grid, qh, kvh, M, V, in_b, out_b, (float*)d_out);
}

// Round 10
// 193.347 us; speedup vs baseline: 1.2265x; 1.2265x over previous
//
#include <hip/hip_runtime.h>
#include <hip/hip_fp16.h>
#include <cstdio>
#include <cstdint>

#define HH 512
#define WW 512
#define CC 32
#define BB 2
#define NN 120000
#define HWPIX (HH*WW)
#define NPTS (BB*NN)          // 240000 occupied points
#define NPIX (BB*HWPIX)       // 524288 pixels (pixel-dense storage)
#define NBLK (NPIX/256)       // 2048 pixel windows

__device__ __forceinline__ void h8_to_f8(float4 raw, float* o) {
    const __half2* h = (const __half2*)&raw;
    #pragma unroll
    for (int i = 0; i < 4; ++i) {
        float2 f = __half22float2(h[i]);
        o[2 * i] = f.x; o[2 * i + 1] = f.y;
    }
}

// ---------------- prep: compose weights + vecs + zero flag map (one kernel) ----------------
// M layout (floats): [0:1024) MqT, [1024:2048) MkT, [2048:3072) MvT, [3072:4096) owT
// V layout (floats): [0:32) bq'=W1@bq+in_b[:32], [32:64) bk'=W2@bk, [64:96) bv'=W3@bv,
// [96:128) PWy, [128:160) PWx, [160:192) pb3=W3@pos_b
__global__ __launch_bounds__(256) void prep(const float* __restrict__ wq, const float* __restrict__ wk,
                          const float* __restrict__ wv, const float* __restrict__ in_w,
                          const float* __restrict__ out_w,
                          const float* __restrict__ bq, const float* __restrict__ bk,
                          const float* __restrict__ bv, const float* __restrict__ in_b,
                          const float* __restrict__ pos_w, const float* __restrict__ pos_b,
                          float* __restrict__ M, float* __restrict__ V, int* __restrict__ fmap_i) {
    int blk = blockIdx.x;
    if (blk < 16) {
        int tid = blk * 256 + threadIdx.x;   // 0..4095
        int which = tid >> 10;
        int e = tid & 1023;
        int cp = e & 31;
        int j  = e >> 5;
        if (which < 3) {
            const float* w = (which == 0) ? wq : ((which == 1) ? wk : wv);
            const float* Wrow = in_w + (which * 32 + cp) * 32;
            float acc = 0.f;
            #pragma unroll
            for (int t = 0; t < 32; ++t) acc += Wrow[t] * w[t * 32 + j];
            M[which * 1024 + j * 32 + cp] = acc;
        } else {
            M[3 * 1024 + j * 32 + cp] = out_w[cp * 32 + j];
        }
    } else if (blk == 16) {
        int tid = threadIdx.x;
        if (tid < 32) {
            float a = 0.f, b = 0.f, c = 0.f;
            #pragma unroll
            for (int t = 0; t < 32; ++t) {
                a += in_w[tid * 32 + t] * bq[t];
                b += in_w[(32 + tid) * 32 + t] * bk[t];
                c += in_w[(64 + tid) * 32 + t] * bv[t];
            }
            V[tid]      = a + in_b[tid];
            V[32 + tid] = b;
            V[64 + tid] = c;
        } else if (tid < 128) {
            int grp = (tid - 32) >> 5;   // 0=PWy 1=PWx 2=pb3
            int cp  = tid & 31;
            float acc = 0.f;
            #pragma unroll
            for (int t = 0; t < 32; ++t) {
                float src = (grp == 0) ? pos_w[t * 2 + 0] : ((grp == 1) ? pos_w[t * 2 + 1] : pos_b[t]);
                acc += in_w[(64 + cp) * 32 + t] * src;
            }
            V[96 + grp * 32 + cp] = acc;
        }
    } else {
        // blocks 17..80: zero the 512 KB flag map (131072 ints; 64 blocks x 256 thr x 8 ints)
        int base = (blk - 17) * 2048 + threadIdx.x * 8;
        int4 z = {0, 0, 0, 0};
        *(int4*)(fmap_i + base)     = z;
        *(int4*)(fmap_i + base + 4) = z;
    }
}

// ---------------- stage1: point-parallel LN + fused q/k/v linears (pixel-dense out) ----------------
// Coalesced feats/coors reads; writes q (64 B) + kv (128 B = 1 line) at pixel slots + flag byte.
__global__ __launch_bounds__(256) void stage1(const float* __restrict__ feats,
                                              const int* __restrict__ coors,
                                              const float* __restrict__ ln_w,
                                              const float* __restrict__ ln_b,
                                              const float* __restrict__ M,
                                              const float* __restrict__ V,
                                              __half* __restrict__ qh,
                                              __half* __restrict__ kvh,
                                              unsigned char* __restrict__ fmap) {
    int gp = blockIdx.x * 256 + threadIdx.x;
    if (gp >= NPTS) return;
    int b = (gp >= NN) ? 1 : 0;
    int2 yx = ((const int2*)coors)[gp];
    int pix = (b << 18) + (yx.x << 9) + yx.y;

    const float* fr = feats + ((size_t)gp << 5);
    float x[32];
    #pragma unroll
    for (int k = 0; k < 8; ++k) ((float4*)x)[k] = ((const float4*)fr)[k];

    float s1 = 0.f, s2 = 0.f;
    #pragma unroll
    for (int j = 0; j < 32; ++j) { s1 += x[j]; s2 += x[j] * x[j]; }
    float mu   = s1 * (1.f / 32.f);
    float var  = s2 * (1.f / 32.f) - mu * mu;
    float rstd = rsqrtf(var + 1e-5f);
    #pragma unroll
    for (int j = 0; j < 32; ++j) x[j] = (x[j] - mu) * rstd * ln_w[j] + ln_b[j];

    float acc[32];
    __half2 hbuf[16];

    // q' = x @ Mq + bq'  -> fp16 at pixel slot
    #pragma unroll
    for (int c = 0; c < 32; ++c) acc[c] = V[c];
    #pragma unroll
    for (int j = 0; j < 32; ++j) {
        float xv = x[j];
        #pragma unroll
        for (int c = 0; c < 32; ++c) acc[c] += xv * M[j * 32 + c];
    }
    #pragma unroll
    for (int c = 0; c < 16; ++c) hbuf[c] = __floats2half2_rn(acc[2 * c], acc[2 * c + 1]);
    {
        float4* qd = (float4*)(qh + ((size_t)pix << 5));
        #pragma unroll
        for (int k = 0; k < 4; ++k) qd[k] = ((float4*)hbuf)[k];
    }

    __half2 kvbuf[32];   // 128 B: k halves [0:16), v halves [16:32)

    // k' = x @ Mk + bk'  -> fp16
    #pragma unroll
    for (int c = 0; c < 32; ++c) acc[c] = V[32 + c];
    #pragma unroll
    for (int j = 0; j < 32; ++j) {
        float xv = x[j];
        #pragma unroll
        for (int c = 0; c < 32; ++c) acc[c] += xv * M[1024 + j * 32 + c];
    }
    #pragma unroll
    for (int c = 0; c < 16; ++c) kvbuf[c] = __floats2half2_rn(acc[2 * c], acc[2 * c + 1]);

    // v' = x @ Mv + bv'  -> fp16
    #pragma unroll
    for (int c = 0; c < 32; ++c) acc[c] = V[64 + c];
    #pragma unroll
    for (int j = 0; j < 32; ++j) {
        float xv = x[j];
        #pragma unroll
        for (int c = 0; c < 32; ++c) acc[c] += xv * M[2048 + j * 32 + c];
    }
    #pragma unroll
    for (int c = 0; c < 16; ++c) kvbuf[16 + c] = __floats2half2_rn(acc[2 * c], acc[2 * c + 1]);

    float4* kd = (float4*)(kvh + ((size_t)pix << 6));
    #pragma unroll
    for (int k = 0; k < 8; ++k) kd[k] = ((float4*)kvbuf)[k];

    fmap[pix] = 1;
}

// ---------------- stage23: fused attention + out-proj + canvas write ----------------
// Block = one 256-pixel window. kv/q addresses are pure pixel arithmetic (no rank
// indirection); flag map (512 KB, L2-resident) gates validity + pos term.
__global__ __launch_bounds__(256) void stage23(const unsigned char* __restrict__ fmap,
                                               const __half* __restrict__ qh,
                                               const __half* __restrict__ kvh,
                                               const float* __restrict__ M,
                                               const float* __restrict__ V,
                                               const float* __restrict__ in_b,
                                               const float* __restrict__ out_b,
                                               float* __restrict__ out) {
    __shared__ __half2 lso[256 * 17];   // 17 half2 (68 B) stride per point
    __shared__ int lsp[256];
    __shared__ int woff[4];

    int w = (blockIdx.x & 7) * 256 + (blockIdx.x >> 3);   // XCD-swizzled window index
    int tid = threadIdx.x;
    int pix = w * 256 + tid;

    bool occ = fmap[pix] != 0;
    unsigned long long mask = __ballot(occ);
    int lane = tid & 63, wvi = tid >> 6;
    if (lane == 0) woff[wvi] = __popcll(mask);
    __syncthreads();
    int pre = 0;
    for (int ww = 0; ww < wvi; ++ww) pre += woff[ww];
    int cnt = woff[0] + woff[1] + woff[2] + woff[3];
    int slot = -1;
    if (occ) {
        slot = pre + __popcll(mask & ((1ull << lane) - 1ull));
        lsp[slot] = tid;
    }
    __syncthreads();

    const int DYC[9] = {0,-1,1,0,-1,1,0,-1,1};
    const int DXC[9] = {0,0,0,1,1,1,-1,-1,-1};

    // ---- phase A: attention, one thread per occupied pixel ----
    if (tid < cnt) {
        int pixl = w * 256 + lsp[tid];
        int b = pixl >> 18;
        int p = pixl & (HWPIX - 1);
        int y = p >> 9, x = p & 511;

        float qf[32];
        {
            const float4* q4 = (const float4*)(qh + ((size_t)pixl << 5));
            float4 r0 = q4[0], r1 = q4[1], r2 = q4[2], r3 = q4[3];
            h8_to_f8(r0, qf); h8_to_f8(r1, qf + 8); h8_to_f8(r2, qf + 16); h8_to_f8(r3, qf + 24);
        }

        // 9 taps: validity is arithmetic + one independent flag byte each (no load chain)
        int np[9];
        bool nv[9];
        #pragma unroll
        for (int s = 0; s < 9; ++s) {
            int sy = y + DYC[s], sx = x + DXC[s];
            bool inb = (sy >= 0) & (sy < HH) & (sx >= 0) & (sx < WW);
            int npx = (b << 18) + (sy << 9) + sx;
            np[s] = npx;
            nv[s] = inb ? (fmap[npx] != 0) : false;
        }

        float eb0 = 0.f, eb1 = 0.f;
        #pragma unroll
        for (int c = 0; c < 16; ++c) {
            eb0 += qf[c]      * in_b[32 + c];
            eb1 += qf[16 + c] * in_b[48 + c];
        }

        float lg0[9], lg1[9];
        #pragma unroll
        for (int s = 0; s < 9; ++s) {
            float d0 = eb0, d1 = eb1;
            if (nv[s]) {
                const float4* kp = (const float4*)(kvh + ((size_t)np[s] << 6));
                float kf[32];
                h8_to_f8(kp[0], kf);      h8_to_f8(kp[1], kf + 8);
                h8_to_f8(kp[2], kf + 16); h8_to_f8(kp[3], kf + 24);
                #pragma unroll
                for (int c = 0; c < 16; ++c) {
                    d0 += qf[c]      * kf[c];
                    d1 += qf[16 + c] * kf[16 + c];
                }
            }
            lg0[s] = d0 * 0.25f;   // 1/sqrt(HD=16)
            lg1[s] = d1 * 0.25f;
        }
        float m0 = lg0[0], m1 = lg1[0];
        #pragma unroll
        for (int s = 1; s < 9; ++s) { m0 = fmaxf(m0, lg0[s]); m1 = fmaxf(m1, lg1[s]); }
        float l0 = 0.f, l1 = 0.f;
        #pragma unroll
        for (int s = 0; s < 9; ++s) {
            lg0[s] = __expf(lg0[s] - m0); l0 += lg0[s];
            lg1[s] = __expf(lg1[s] - m1); l1 += lg1[s];
        }

        float o[32];
        #pragma unroll
        for (int c = 0; c < 32; ++c) o[c] = 0.f;
        float wdy0 = 0.f, wdx0 = 0.f, woc0 = 0.f;
        float wdy1 = 0.f, wdx1 = 0.f, woc1 = 0.f;
        #pragma unroll
        for (int s = 0; s < 9; ++s) {
            if (nv[s]) {
                float w0 = lg0[s], w1 = lg1[s];
                const float4* vp = (const float4*)(kvh + ((size_t)np[s] << 6)) + 4;
                float vf[32];
                h8_to_f8(vp[0], vf);      h8_to_f8(vp[1], vf + 8);
                h8_to_f8(vp[2], vf + 16); h8_to_f8(vp[3], vf + 24);
                #pragma unroll
                for (int c = 0; c < 16; ++c) {
                    o[c]      += w0 * vf[c];
                    o[16 + c] += w1 * vf[16 + c];
                }
                wdy0 += w0 * (float)DYC[s]; wdx0 += w0 * (float)DXC[s]; woc0 += w0;
                wdy1 += w1 * (float)DYC[s]; wdx1 += w1 * (float)DXC[s]; woc1 += w1;
            }
        }
        float rl0 = 1.f / l0, rl1 = 1.f / l1;
        #pragma unroll
        for (int c = 0; c < 16; ++c) {
            o[c]      = (o[c]      + wdy0 * V[96 + c]      + wdx0 * V[128 + c]      + woc0 * V[160 + c])      * rl0 + in_b[64 + c];
            o[16 + c] = (o[16 + c] + wdy1 * V[96 + 16 + c] + wdx1 * V[128 + 16 + c] + woc1 * V[160 + 16 + c]) * rl1 + in_b[80 + c];
        }

        // out projection: all 32 channels, wave-uniform (scalarized) weights
        float acc[32];
        #pragma unroll
        for (int c = 0; c < 32; ++c) acc[c] = out_b[c];
        #pragma unroll
        for (int j = 0; j < 32; ++j) {
            float vj = o[j];
            #pragma unroll
            for (int c = 0; c < 32; ++c) acc[c] += vj * M[3072 + j * 32 + c];
        }

        // pack fp16 into LDS row (stride 17 half2)
        __half2* lrow = lso + tid * 17;
        #pragma unroll
        for (int c = 0; c < 16; ++c) lrow[c] = __floats2half2_rn(acc[2 * c], acc[2 * c + 1]);
    }
    __syncthreads();

    // ---- phase B: canvas write (all 256 threads; 256 B contiguous per wave-instr) ----
    int b = pix >> 18;
    int p = pix & (HWPIX - 1);
    float* outb = out + (size_t)b * CC * HWPIX + p;
    if (occ) {
        const __half2* lrow = lso + slot * 17;
        #pragma unroll
        for (int c2 = 0; c2 < 16; ++c2) {
            float2 f = __half22float2(lrow[c2]);
            outb[(2 * c2) * HWPIX]     = f.x;
            outb[(2 * c2 + 1) * HWPIX] = f.y;
        }
    } else {
        #pragma unroll
        for (int cc = 0; cc < 32; ++cc) outb[cc * HWPIX] = 0.f;
    }
}

extern "C" void kernel_launch(void* const* d_in, const int* in_sizes, int n_in,
                              void* d_out, int out_size, void* d_ws, size_t ws_size,
                              hipStream_t stream) {
    const float* feats = (const float*)d_in[0];
    const int*   coors = (const int*)d_in[1];
    const float* ln_w  = (const float*)d_in[2];
    const float* ln_b  = (const float*)d_in[3];
    const float* wq    = (const float*)d_in[4];
    const float* bq    = (const float*)d_in[5];
    const float* wk    = (const float*)d_in[6];
    const float* bk    = (const float*)d_in[7];
    const float* wv    = (const float*)d_in[8];
    const float* bv    = (const float*)d_in[9];
    const float* pos_w = (const float*)d_in[10];
    const float* pos_b = (const float*)d_in[11];
    const float* in_w  = (const float*)d_in[12];
    const float* in_b  = (const float*)d_in[13];
    const float* out_w = (const float*)d_in[14];
    const float* out_b = (const float*)d_in[15];

    // workspace layout (pixel-dense)
    float*  M    = (float*)d_ws;                                        // 4096
    float*  V    = M + 4096;                                            // 192
    __half* qh   = (__half*)(V + 192);                                  // NPIX*32 halves (33.5 MB)
    __half* kvh  = qh + (size_t)NPIX * 32;                              // NPIX*64 halves (67.1 MB)
    unsigned char* fmap = (unsigned char*)(kvh + (size_t)NPIX * 64);    // NPIX bytes (0.5 MB)
    size_t need = (4096 + 192) * 4 + (size_t)NPIX * 96 * 2 + (size_t)NPIX;
    if (ws_size < need) {
        fprintf(stderr, "kernel_launch: ws too small: %zu < %zu\n", ws_size, need);
        return;
    }

    prep<<<81, 256, 0, stream>>>(wq, wk, wv, in_w, out_w, bq, bk, bv, in_b, pos_w, pos_b,
                                 M, V, (int*)fmap);
    stage1<<<(NPTS + 255) / 256, 256, 0, stream>>>(feats, coors, ln_w, ln_b, M, V, qh, kvh, fmap);
    stage23<<<NBLK, 256, 0, stream>>>(fmap, qh, kvh, M, V, in_b, out_b, (float*)d_out);
}